// Round 4
// baseline (310.875 us; speedup 1.0000x reference)
//
#include <hip/hip_runtime.h>
#include <hip/hip_cooperative_groups.h>

namespace cg = cooperative_groups;

#define NN 512
#define DD 64
#define TOPK 20
#define BB 128

struct Ptrs {
    const float *data, *emb, *fc_w, *fc_b, *attn_w, *attn_b, *gamma, *beta, *out_w, *out_b;
    float *z, *rst, *zsrc, *zdst;
    int *topk;
    float *es_src, *es_dst;
    double *nrm, *gstats;
    float *out;
};

// ---------------- P0: norms (f64, same accumulation order as verified topk),
// emb-attn partial scores, zero global stats ----------------------------------
__device__ __forceinline__ void phase0(const Ptrs& P) {
    const int bid = blockIdx.x, t = threadIdx.x;
    if (bid < 2) {
        const int j = bid * 256 + t;
        const float4* e4 = (const float4*)P.emb;
        double s = 0.0;
        for (int c = 0; c < 16; ++c) {
            float4 v = e4[j * 16 + c];
            double vx = v.x, vy = v.y, vz = v.z, vw = v.w;
            s += vx * vx; s += vy * vy; s += vz * vz; s += vw * vw;
        }
        P.nrm[j] = sqrt(s);
    } else if (bid < 4) {
        const int j = (bid - 2) * 256 + t;
        float s1 = 0.f, s2 = 0.f;
        for (int c = 0; c < 64; ++c) {
            const float w = P.emb[j * 64 + c];
            s1 += w * P.attn_w[64 + c];
            s2 += w * P.attn_w[192 + c];
        }
        P.es_src[j] = s1;
        P.es_dst[j] = s2;
    } else if (bid == 4) {
        if (t < 128) P.gstats[t] = 0.0;
    }
}

// ---------------- P1: blocks 0..383 GEMM tiles, blocks 384..511 topk ----------
__device__ __forceinline__ void phase1(const Ptrs& P, char* smem) {
    const int bid = blockIdx.x, t = threadIdx.x;
    if (bid < 384) {
        float (*As)[68]   = (float(*)[68])smem;
        float (*WsT)[68]  = (float(*)[68])(smem + 17408);
        float (*redA)[17] = (float(*)[17])(smem + 34816);
        float (*redB)[17] = (float(*)[17])(smem + 39168);
        const float4* data4 = (const float4*)P.data;
        const float4* fcw4  = (const float4*)P.fc_w;

        for (int it = 0; it < 3; ++it) {
            const int tile = it * 384 + bid;
            if (tile >= 1024) break;
            const long r0 = (long)tile * 64;
            __syncthreads();
            {
                const int r = t >> 4, c4 = t & 15;
                #pragma unroll
                for (int rr = 0; rr < 4; ++rr)
                    *(float4*)&As[r * 4 + rr][c4 * 4] = data4[(r0 + r * 4 + rr) * 16 + c4];
                #pragma unroll
                for (int dd2 = 0; dd2 < 4; ++dd2) {
                    const int d = r * 4 + dd2;
                    float4 v = fcw4[d * 16 + c4];
                    WsT[c4 * 4 + 0][d] = v.x;
                    WsT[c4 * 4 + 1][d] = v.y;
                    WsT[c4 * 4 + 2][d] = v.z;
                    WsT[c4 * 4 + 3][d] = v.w;
                }
            }
            __syncthreads();

            const int tr = t >> 4, tc = t & 15;
            float acc[4][4] = {};
            for (int k0 = 0; k0 < 64; k0 += 4) {
                float4 a4[4], b4[4];
                #pragma unroll
                for (int i = 0; i < 4; ++i) a4[i] = *(float4*)&As[tr * 4 + i][k0];
                #pragma unroll
                for (int kk = 0; kk < 4; ++kk) b4[kk] = *(float4*)&WsT[k0 + kk][tc * 4];
                #pragma unroll
                for (int i = 0; i < 4; ++i) {
                    acc[i][0] += a4[i].x * b4[0].x + a4[i].y * b4[1].x + a4[i].z * b4[2].x + a4[i].w * b4[3].x;
                    acc[i][1] += a4[i].x * b4[0].y + a4[i].y * b4[1].y + a4[i].z * b4[2].y + a4[i].w * b4[3].y;
                    acc[i][2] += a4[i].x * b4[0].z + a4[i].y * b4[1].z + a4[i].z * b4[2].z + a4[i].w * b4[3].z;
                    acc[i][3] += a4[i].x * b4[0].w + a4[i].y * b4[1].w + a4[i].z * b4[2].w + a4[i].w * b4[3].w;
                }
            }
            float bias[4], aw0[4], aw2[4];
            #pragma unroll
            for (int j = 0; j < 4; ++j) {
                bias[j] = P.fc_b[tc * 4 + j];
                aw0[j]  = P.attn_w[tc * 4 + j];
                aw2[j]  = P.attn_w[128 + tc * 4 + j];
            }
            #pragma unroll
            for (int i = 0; i < 4; ++i) {
                float zb[4];
                #pragma unroll
                for (int j = 0; j < 4; ++j) zb[j] = acc[i][j] + bias[j];
                float4 vv; vv.x = zb[0]; vv.y = zb[1]; vv.z = zb[2]; vv.w = zb[3];
                *(float4*)&P.z[(r0 + tr * 4 + i) * 64 + tc * 4] = vv;
                redA[tr * 4 + i][tc] = zb[0] * aw0[0] + zb[1] * aw0[1] + zb[2] * aw0[2] + zb[3] * aw0[3];
                redB[tr * 4 + i][tc] = zb[0] * aw2[0] + zb[1] * aw2[1] + zb[2] * aw2[2] + zb[3] * aw2[3];
            }
            __syncthreads();
            if (t < 64) {
                float sA = 0.f, sB = 0.f;
                #pragma unroll
                for (int k = 0; k < 16; ++k) { sA += redA[t][k]; sB += redB[t][k]; }
                P.zsrc[r0 + t] = sA;
                P.zdst[r0 + t] = sB;
            }
        }
    } else {
        // topk: one wave per node; dot-only (norms precomputed); bit-identical
        // accumulation order & tie-break to verified rounds.
        const int i = (bid - 384) * 4 + (t >> 6);
        const int lane = t & 63;
        const float4* e4 = (const float4*)P.emb;

        double dot[8] = {0,0,0,0,0,0,0,0};
        for (int c = 0; c < 16; ++c) {
            float4 wi4 = e4[i * 16 + c];
            double wx = wi4.x, wy = wi4.y, wz = wi4.z, ww = wi4.w;
            #pragma unroll
            for (int r = 0; r < 8; ++r) {
                float4 v = e4[(lane * 8 + r) * 16 + c];
                double vx = v.x, vy = v.y, vz = v.z, vw = v.w;
                dot[r] += wx * vx; dot[r] += wy * vy; dot[r] += wz * vz; dot[r] += ww * vw;
            }
        }
        const double nrm_i = P.nrm[i];
        double v[8];
        #pragma unroll
        for (int r = 0; r < 8; ++r) v[r] = dot[r] / (nrm_i * P.nrm[lane * 8 + r]);

        for (int k = 0; k < TOPK; ++k) {
            double bv = v[0]; int br = 0;
            #pragma unroll
            for (int r = 1; r < 8; ++r) if (v[r] > bv) { bv = v[r]; br = r; }
            int bi = lane * 8 + br;
            #pragma unroll
            for (int off = 32; off > 0; off >>= 1) {
                double ov = __shfl_xor(bv, off);
                int    oi = __shfl_xor(bi, off);
                if (ov > bv || (ov == bv && oi < bi)) { bv = ov; bi = oi; }
            }
            if (lane == 0) P.topk[i * TOPK + k] = bi;
            if ((bi >> 3) == lane) v[bi & 7] = -1e300;
        }
    }
}

// ---------------- P2: LDS-staged gather + one-shot softmax + BN atomics -------
__device__ __forceinline__ void phase2(const Ptrs& P, char* smem) {
    float*  zs   = (float*)smem;                         // 32 KB
    float4* zs4  = (float4*)smem;
    float*  alf  = (float*)(smem + 32768);               // 20 KB
    double* rdbl = (double*)(smem + 32768);
    unsigned short* sIdx = (unsigned short*)(smem + 53248); // 10 KB

    const int bid  = blockIdx.x;
    const int b    = bid >> 2;
    const int dq   = bid & 3;
    const int doff = dq * 16;
    const int t    = threadIdx.x;
    const float attn_b = *P.attn_b;
    const long b512 = (long)b * NN;

    for (int m = t; m < 2048; m += 256) {
        const int n = m >> 2, c4i = m & 3;
        zs4[m] = *(const float4*)(P.z + (b512 + n) * 64 + doff + c4i * 4);
    }
    __syncthreads();

    const int c4 = t & 3;
    const int rq = t >> 2;
    double s1[4] = {0,0,0,0}, s2[4] = {0,0,0,0};

    for (int chunk = 0; chunk < 2; ++chunk) {
        {
            const int n = chunk * 256 + t;
            const float sd = P.zdst[b512 + n] + P.es_dst[n] + attn_b;
            float ev[TOPK];
            float m0 = -1e30f;
            #pragma unroll
            for (int tt = 0; tt < TOPK; ++tt) {
                const int s = P.topk[n + tt * NN];   // scrambled flat edge list
                sIdx[t * TOPK + tt] = (unsigned short)s;
                float e = P.zsrc[b512 + s] + P.es_src[s] + sd;
                e = (e >= 0.f) ? e : 0.2f * e;
                ev[tt] = e;
                m0 = fmaxf(m0, e);
            }
            float dsum = 0.f;
            #pragma unroll
            for (int tt = 0; tt < TOPK; ++tt) { ev[tt] = __expf(ev[tt] - m0); dsum += ev[tt]; }
            const float inv = 1.0f / dsum;
            #pragma unroll
            for (int tt = 0; tt < TOPK; ++tt) alf[t * TOPK + tt] = ev[tt] * inv;
        }
        __syncthreads();

        #pragma unroll
        for (int it = 0; it < 4; ++it) {
            const int nl = it * 64 + rq;
            const int n  = chunk * 256 + nl;
            float4 acc = {0.f, 0.f, 0.f, 0.f};
            #pragma unroll
            for (int tt = 0; tt < TOPK; ++tt) {
                const float a = alf[nl * TOPK + tt];
                const float4 zv = zs4[(int)sIdx[nl * TOPK + tt] * 4 + c4];
                acc.x += a * zv.x; acc.y += a * zv.y; acc.z += a * zv.z; acc.w += a * zv.w;
            }
            const float4 ev = *(const float4*)&P.emb[n * 64 + doff + c4 * 4];
            float4 r;
            r.x = acc.x * ev.x; r.y = acc.y * ev.y; r.z = acc.z * ev.z; r.w = acc.w * ev.w;
            *(float4*)&P.rst[(b512 + n) * 64 + doff + c4 * 4] = r;
            s1[0] += (double)r.x; s2[0] += (double)r.x * (double)r.x;
            s1[1] += (double)r.y; s2[1] += (double)r.y * (double)r.y;
            s1[2] += (double)r.z; s2[2] += (double)r.z * (double)r.z;
            s1[3] += (double)r.w; s2[3] += (double)r.w * (double)r.w;
        }
        __syncthreads();
    }

    double* r1 = rdbl;
    double* r2 = rdbl + 1024;
    #pragma unroll
    for (int j = 0; j < 4; ++j) {
        r1[(c4 * 4 + j) * 64 + rq] = s1[j];
        r2[(c4 * 4 + j) * 64 + rq] = s2[j];
    }
    __syncthreads();
    if (t < 16) {
        double a = 0.0, bb = 0.0;
        for (int q = 0; q < 64; ++q) { a += r1[t * 64 + q]; bb += r2[t * 64 + q]; }
        atomicAdd(&P.gstats[dq * 16 + t], a);
        atomicAdd(&P.gstats[64 + dq * 16 + t], bb);
    }
}

// ---------------- P3: BN finalize (per-block, redundant) + out ----------------
__device__ __forceinline__ void phase3(const Ptrs& P, char* smem) {
    float* scv = (float*)smem;
    float* biv = (float*)(smem + 256);
    const int bid = blockIdx.x, t = threadIdx.x;

    __syncthreads();
    if (t < 64) {
        const double M = (double)BB * (double)NN;
        const double s  = P.gstats[t];
        const double s2 = P.gstats[64 + t];
        const double mu  = s / M;
        const double var = s2 / M - mu * mu;
        const float scale = (float)((double)P.gamma[t] / sqrt(var + 1e-5));
        scv[t] = scale;
        biv[t] = P.beta[t] - (float)mu * scale;
    }
    __syncthreads();

    const int wid = t >> 6, lane = t & 63;
    const float sc = scv[lane], bi = biv[lane], ow = P.out_w[lane];
    const float ob = *P.out_b;
    #pragma unroll
    for (int it = 0; it < 8; ++it) {
        const long rowbase = (long)bid * 128 + it * 16 + wid * 4;
        float v[4];
        #pragma unroll
        for (int rr = 0; rr < 4; ++rr)
            v[rr] = fmaxf(P.rst[(rowbase + rr) * 64 + lane] * sc + bi, 0.f) * ow;
        #pragma unroll
        for (int off = 32; off > 0; off >>= 1)
            #pragma unroll
            for (int rr = 0; rr < 4; ++rr) v[rr] += __shfl_down(v[rr], off);
        if (lane == 0)
            #pragma unroll
            for (int rr = 0; rr < 4; ++rr) P.out[rowbase + rr] = v[rr] + ob;
    }
}

// phase = -1 : cooperative, all phases with grid.sync
// phase = 0..3 : single phase (fallback multi-launch path)
__global__ __launch_bounds__(256, 2) void fused_all(Ptrs P, int phase) {
    __shared__ __align__(16) char smem[63488];
    if (phase < 0) {
        cg::grid_group g = cg::this_grid();
        phase0(P);        g.sync();
        phase1(P, smem);  g.sync();
        phase2(P, smem);  g.sync();
        phase3(P, smem);
    } else if (phase == 0) phase0(P);
    else if (phase == 1) phase1(P, smem);
    else if (phase == 2) phase2(P, smem);
    else phase3(P, smem);
}

extern "C" void kernel_launch(void* const* d_in, const int* in_sizes, int n_in,
                              void* d_out, int out_size, void* d_ws, size_t ws_size,
                              hipStream_t stream) {
    char* ws = (char*)d_ws;
    Ptrs P;
    P.data   = (const float*)d_in[0];
    P.emb    = (const float*)d_in[1];
    P.fc_w   = (const float*)d_in[2];
    P.fc_b   = (const float*)d_in[3];
    P.attn_w = (const float*)d_in[4];
    P.attn_b = (const float*)d_in[5];
    P.gamma  = (const float*)d_in[6];
    P.beta   = (const float*)d_in[7];
    P.out_w  = (const float*)d_in[8];
    P.out_b  = (const float*)d_in[9];
    P.z      = (float*) (ws + 0);            // 16 MB
    P.rst    = (float*) (ws + 16777216);     // 16 MB
    P.zsrc   = (float*) (ws + 33554432);     // 256 KB
    P.zdst   = (float*) (ws + 33816576);     // 256 KB
    P.topk   = (int*)   (ws + 34078720);     // 40 KB
    P.es_src = (float*) (ws + 34119680);     // 2 KB
    P.es_dst = (float*) (ws + 34121728);     // 2 KB
    P.nrm    = (double*)(ws + 34123776);     // 4 KB
    P.gstats = (double*)(ws + 34127872);     // 1 KB
    P.out    = (float*)d_out;

    int phase = -1;
    void* kargs[] = { (void*)&P, (void*)&phase };
    hipError_t err = hipLaunchCooperativeKernel((const void*)fused_all,
                                                dim3(512), dim3(256), kargs, 0, stream);
    if (err != hipSuccess) {
        (void)hipGetLastError();   // clear sticky error, fall back to 4 launches
        for (int ph = 0; ph < 4; ++ph)
            fused_all<<<dim3(512), dim3(256), 0, stream>>>(P, ph);
    }
}

// Round 5
// 162.606 us; speedup vs baseline: 1.9118x; 1.9118x over previous
//
#include <hip/hip_runtime.h>
#include <hip/hip_bf16.h>

#define NN 512
#define DD 64
#define TOPK 20
#define BB 128

// ---------------- K1: cos topk (LDS-staged, coalesced) + emb-attn partials ------
// row <-> (slot,lane) mapping: row = slot*64 + lane. Per-row f64 arithmetic has
// the exact accumulation order of the verified round-2 kernel (c ascending,
// x,y,z,w) -> v[row] bit-identical; tie-break = smallest row index -> identical
// topk output. Also zeroes gstats (block 0) for k3's BN atomics.
__global__ __launch_bounds__(256) void k1_topk(const float* __restrict__ emb,
                                               const float* __restrict__ attn_w,
                                               int* __restrict__ topk,
                                               float* __restrict__ es_src,
                                               float* __restrict__ es_dst,
                                               double* __restrict__ gstats) {
    __shared__ float4 lds4[2048];     // 32 KB, XOR-swizzled [row][c^(row&15)]
    const int bid = blockIdx.x, t = threadIdx.x;
    const int wid = t >> 6, lane = t & 63;
    const int i = bid * 4 + wid;
    const float4* e4 = (const float4*)emb;

    if (bid == 0 && t < 128) gstats[t] = 0.0;

    // wi in registers (wave-uniform)
    float4 wif[16];
    #pragma unroll
    for (int c = 0; c < 16; ++c) wif[c] = e4[i * 16 + c];

    double di = 0.0;
    #pragma unroll
    for (int c = 0; c < 16; ++c) {
        double wx = wif[c].x, wy = wif[c].y, wz = wif[c].z, ww = wif[c].w;
        di += wx * wx; di += wy * wy; di += wz * wz; di += ww * ww;
    }

    double dot[8] = {0,0,0,0,0,0,0,0};
    double dj [8] = {0,0,0,0,0,0,0,0};

    for (int tile = 0; tile < 4; ++tile) {
        __syncthreads();
        for (int m = t; m < 2048; m += 256) {
            const int row = m >> 4, c = m & 15;
            lds4[row * 16 + (c ^ (row & 15))] = e4[tile * 2048 + m];  // coalesced read
        }
        __syncthreads();
        #pragma unroll
        for (int rb = 0; rb < 2; ++rb) {
            const int slot = tile * 2 + rb;
            const int rl = rb * 64 + lane;
            const int rx = rl & 15;
            #pragma unroll
            for (int c = 0; c < 16; ++c) {
                float4 v = lds4[rl * 16 + (c ^ rx)];
                float4 w = wif[c];
                double vx = v.x, vy = v.y, vz = v.z, vw = v.w;
                dot[slot] += (double)w.x * vx; dot[slot] += (double)w.y * vy;
                dot[slot] += (double)w.z * vz; dot[slot] += (double)w.w * vw;
                dj [slot] += vx * vx; dj[slot] += vy * vy; dj[slot] += vz * vz; dj[slot] += vw * vw;
            }
        }
    }

    const double nrm_i = sqrt(di);
    double v[8];
    #pragma unroll
    for (int s = 0; s < 8; ++s) v[s] = dot[s] / (nrm_i * sqrt(dj[s]));

    for (int k = 0; k < TOPK; ++k) {
        double bv = v[0]; int bs = 0;
        #pragma unroll
        for (int s = 1; s < 8; ++s) if (v[s] > bv) { bv = v[s]; bs = s; }
        int bi = bs * 64 + lane;   // actual row index
        #pragma unroll
        for (int off = 32; off > 0; off >>= 1) {
            double ov = __shfl_xor(bv, off);
            int    oi = __shfl_xor(bi, off);
            if (ov > bv || (ov == bv && oi < bi)) { bv = ov; bi = oi; }
        }
        if (lane == 0) topk[i * TOPK + k] = bi;
        if ((bi & 63) == lane) v[bi >> 6] = -1e300;
    }

    // es_src[i] = emb[i,:].attn_w[64:128]; es_dst[i] = emb[i,:].attn_w[192:256]
    float wf = emb[i * 64 + lane];
    float v1 = wf * attn_w[64 + lane];
    float v2 = wf * attn_w[192 + lane];
    #pragma unroll
    for (int off = 32; off > 0; off >>= 1) {
        v1 += __shfl_xor(v1, off);
        v2 += __shfl_xor(v2, off);
    }
    if (lane == 0) { es_src[i] = v1; es_dst[i] = v2; }
}

// ---------------- K2: z = data @ fc_w^T + fc_b, fused z-attn partial scores -----
__global__ __launch_bounds__(256) void k2_gemm(const float* __restrict__ data,
                                               const float* __restrict__ fc_w,
                                               const float* __restrict__ fc_b,
                                               const float* __restrict__ attn_w,
                                               float* __restrict__ z,
                                               float* __restrict__ zsrc,
                                               float* __restrict__ zdst) {
    __shared__ float As [64][68];
    __shared__ float WsT[64][68];   // WsT[f][d] = fc_w[d][f]
    __shared__ float redA[64][17];
    __shared__ float redB[64][17];
    const int t = threadIdx.x;
    const long r0 = (long)blockIdx.x * 64;
    const float4* data4 = (const float4*)data;
    const float4* fcw4  = (const float4*)fc_w;

    for (int m = t; m < 1024; m += 256) {
        const int r = m >> 4, c4 = m & 15;
        *(float4*)&As[r][c4 * 4] = data4[(r0 + r) * 16 + c4];
    }
    for (int m = t; m < 1024; m += 256) {
        const int d = m >> 4, f4 = m & 15;
        float4 v = fcw4[d * 16 + f4];
        WsT[f4 * 4 + 0][d] = v.x;
        WsT[f4 * 4 + 1][d] = v.y;
        WsT[f4 * 4 + 2][d] = v.z;
        WsT[f4 * 4 + 3][d] = v.w;
    }
    __syncthreads();

    const int tr = t >> 4, tc = t & 15;
    float acc[4][4] = {};
    for (int k0 = 0; k0 < 64; k0 += 4) {
        float4 a4[4], b4[4];
        #pragma unroll
        for (int i = 0; i < 4; ++i) a4[i] = *(float4*)&As[tr * 4 + i][k0];
        #pragma unroll
        for (int kk = 0; kk < 4; ++kk) b4[kk] = *(float4*)&WsT[k0 + kk][tc * 4];
        #pragma unroll
        for (int i = 0; i < 4; ++i) {
            acc[i][0] += a4[i].x * b4[0].x + a4[i].y * b4[1].x + a4[i].z * b4[2].x + a4[i].w * b4[3].x;
            acc[i][1] += a4[i].x * b4[0].y + a4[i].y * b4[1].y + a4[i].z * b4[2].y + a4[i].w * b4[3].y;
            acc[i][2] += a4[i].x * b4[0].z + a4[i].y * b4[1].z + a4[i].z * b4[2].z + a4[i].w * b4[3].z;
            acc[i][3] += a4[i].x * b4[0].w + a4[i].y * b4[1].w + a4[i].z * b4[2].w + a4[i].w * b4[3].w;
        }
    }
    float bias[4], aw0[4], aw2[4];
    #pragma unroll
    for (int j = 0; j < 4; ++j) {
        bias[j] = fc_b[tc * 4 + j];
        aw0[j]  = attn_w[tc * 4 + j];
        aw2[j]  = attn_w[128 + tc * 4 + j];
    }
    #pragma unroll
    for (int i = 0; i < 4; ++i) {
        float zb[4];
        #pragma unroll
        for (int j = 0; j < 4; ++j) zb[j] = acc[i][j] + bias[j];
        float4 vv; vv.x = zb[0]; vv.y = zb[1]; vv.z = zb[2]; vv.w = zb[3];
        *(float4*)&z[(r0 + tr * 4 + i) * 64 + tc * 4] = vv;
        redA[tr * 4 + i][tc] = zb[0] * aw0[0] + zb[1] * aw0[1] + zb[2] * aw0[2] + zb[3] * aw0[3];
        redB[tr * 4 + i][tc] = zb[0] * aw2[0] + zb[1] * aw2[1] + zb[2] * aw2[2] + zb[3] * aw2[3];
    }
    __syncthreads();
    if (t < 64) {
        float sA = 0.f, sB = 0.f;
        #pragma unroll
        for (int k = 0; k < 16; ++k) { sA += redA[t][k]; sB += redB[t][k]; }
        zsrc[r0 + t] = sA;
        zdst[r0 + t] = sB;
    }
}

// ---------------- K3: LDS-staged gather + one-shot softmax + BN atomics ---------
__global__ __launch_bounds__(256) void k3_attn(const float* __restrict__ z,
                                               const float* __restrict__ zsrc,
                                               const float* __restrict__ zdst,
                                               const float* __restrict__ es_src,
                                               const float* __restrict__ es_dst,
                                               const int* __restrict__ topk,
                                               const float* __restrict__ emb,
                                               const float* __restrict__ attn_b_p,
                                               float* __restrict__ rst,
                                               double* __restrict__ gstats) {
    __shared__ float  zs[512 * 16];          // 32 KB
    __shared__ double alf_pool[2560];        // 20 KB: alpha[256][20] / BN-reduce alias
    __shared__ unsigned short sIdx[256 * 20];// 10 KB
    float* alf = (float*)alf_pool;

    const int b    = blockIdx.x >> 2;
    const int dq   = blockIdx.x & 3;
    const int doff = dq * 16;
    const int t    = threadIdx.x;
    const float attn_b = *attn_b_p;
    const long b512 = (long)b * NN;

    float4* zs4 = (float4*)zs;
    for (int m = t; m < 2048; m += 256) {
        const int n = m >> 2, c4i = m & 3;
        zs4[m] = *(const float4*)(z + (b512 + n) * 64 + doff + c4i * 4);
    }
    __syncthreads();

    const int c4 = t & 3;
    const int rq = t >> 2;
    double s1[4] = {0,0,0,0}, s2[4] = {0,0,0,0};

    for (int chunk = 0; chunk < 2; ++chunk) {
        {
            const int n = chunk * 256 + t;
            const float sd = zdst[b512 + n] + es_dst[n] + attn_b;
            float ev[TOPK];
            float m0 = -1e30f;
            #pragma unroll
            for (int tt = 0; tt < TOPK; ++tt) {
                const int s = topk[n + tt * NN];   // scrambled flat edge list
                sIdx[t * TOPK + tt] = (unsigned short)s;
                float e = zsrc[b512 + s] + es_src[s] + sd;
                e = (e >= 0.f) ? e : 0.2f * e;
                ev[tt] = e;
                m0 = fmaxf(m0, e);
            }
            float dsum = 0.f;
            #pragma unroll
            for (int tt = 0; tt < TOPK; ++tt) { ev[tt] = __expf(ev[tt] - m0); dsum += ev[tt]; }
            const float inv = 1.0f / dsum;
            #pragma unroll
            for (int tt = 0; tt < TOPK; ++tt) alf[t * TOPK + tt] = ev[tt] * inv;
        }
        __syncthreads();

        #pragma unroll
        for (int it = 0; it < 4; ++it) {
            const int nl = it * 64 + rq;
            const int n  = chunk * 256 + nl;
            float4 acc = {0.f, 0.f, 0.f, 0.f};
            #pragma unroll
            for (int tt = 0; tt < TOPK; ++tt) {
                const float a = alf[nl * TOPK + tt];
                const float4 zv = zs4[(int)sIdx[nl * TOPK + tt] * 4 + c4];
                acc.x += a * zv.x; acc.y += a * zv.y; acc.z += a * zv.z; acc.w += a * zv.w;
            }
            const float4 ev = *(const float4*)&emb[n * 64 + doff + c4 * 4];
            float4 r;
            r.x = acc.x * ev.x; r.y = acc.y * ev.y; r.z = acc.z * ev.z; r.w = acc.w * ev.w;
            *(float4*)&rst[(b512 + n) * 64 + doff + c4 * 4] = r;
            s1[0] += (double)r.x; s2[0] += (double)r.x * (double)r.x;
            s1[1] += (double)r.y; s2[1] += (double)r.y * (double)r.y;
            s1[2] += (double)r.z; s2[2] += (double)r.z * (double)r.z;
            s1[3] += (double)r.w; s2[3] += (double)r.w * (double)r.w;
        }
        __syncthreads();
    }

    double* r1 = alf_pool;
    double* r2 = alf_pool + 1024;
    #pragma unroll
    for (int j = 0; j < 4; ++j) {
        r1[(c4 * 4 + j) * 64 + rq] = s1[j];
        r2[(c4 * 4 + j) * 64 + rq] = s2[j];
    }
    __syncthreads();
    if (t < 16) {
        double a = 0.0, bb = 0.0;
        for (int q = 0; q < 64; ++q) { a += r1[t * 64 + q]; bb += r2[t * 64 + q]; }
        atomicAdd(&gstats[doff + t], a);
        atomicAdd(&gstats[64 + doff + t], bb);
    }
}

// ---------------- K5: BN finalize (per-block) + apply + ReLU + out_w dot --------
__global__ __launch_bounds__(256) void k5_out(const float* __restrict__ rst,
                                              const double* __restrict__ gstats,
                                              const float* __restrict__ gamma,
                                              const float* __restrict__ beta,
                                              const float* __restrict__ out_w,
                                              const float* __restrict__ out_b_p,
                                              float* __restrict__ out) {
    __shared__ float scv[64], biv[64];
    const int t = threadIdx.x;
    if (t < 64) {
        const double M = (double)BB * (double)NN;
        const double s  = gstats[t];
        const double s2 = gstats[64 + t];
        const double mu  = s / M;
        const double var = s2 / M - mu * mu;
        const float scale = (float)((double)gamma[t] / sqrt(var + 1e-5));
        scv[t] = scale;
        biv[t] = beta[t] - (float)mu * scale;
    }
    __syncthreads();

    const int wid = t >> 6, lane = t & 63;
    const float sc = scv[lane], bi = biv[lane], ow = out_w[lane];
    const float ob = *out_b_p;
    const long rowbase = (long)blockIdx.x * 16 + wid * 4;
    float v[4];
    #pragma unroll
    for (int rr = 0; rr < 4; ++rr)
        v[rr] = fmaxf(rst[(rowbase + rr) * 64 + lane] * sc + bi, 0.f) * ow;
    #pragma unroll
    for (int off = 32; off > 0; off >>= 1)
        #pragma unroll
        for (int rr = 0; rr < 4; ++rr) v[rr] += __shfl_down(v[rr], off);
    if (lane == 0)
        #pragma unroll
        for (int rr = 0; rr < 4; ++rr) out[rowbase + rr] = v[rr] + ob;
}

extern "C" void kernel_launch(void* const* d_in, const int* in_sizes, int n_in,
                              void* d_out, int out_size, void* d_ws, size_t ws_size,
                              hipStream_t stream) {
    const float* data   = (const float*)d_in[0];
    const float* emb    = (const float*)d_in[1];
    const float* fc_w   = (const float*)d_in[2];
    const float* fc_b   = (const float*)d_in[3];
    const float* attn_w = (const float*)d_in[4];
    const float* attn_b = (const float*)d_in[5];
    const float* gamma  = (const float*)d_in[6];
    const float* beta   = (const float*)d_in[7];
    const float* out_w  = (const float*)d_in[8];
    const float* out_b  = (const float*)d_in[9];
    float* out = (float*)d_out;

    char* ws = (char*)d_ws;
    float*  z      = (float*) (ws + 0);            // 16 MB
    float*  rst    = (float*) (ws + 16777216);     // 16 MB
    float*  zsrc   = (float*) (ws + 33554432);     // 256 KB
    float*  zdst   = (float*) (ws + 33816576);     // 256 KB
    int*    topk   = (int*)   (ws + 34078720);     // 40 KB
    float*  es_src = (float*) (ws + 34119680);     // 2 KB
    float*  es_dst = (float*) (ws + 34121728);     // 2 KB
    double* gstats = (double*)(ws + 34123776);     // 1 KB

    k1_topk<<<128, 256, 0, stream>>>(emb, attn_w, topk, es_src, es_dst, gstats);
    k2_gemm<<<1024, 256, 0, stream>>>(data, fc_w, fc_b, attn_w, z, zsrc, zdst);
    k3_attn<<<BB * 4, 256, 0, stream>>>(z, zsrc, zdst, es_src, es_dst, topk, emb,
                                        attn_b, rst, gstats);
    k5_out<<<4096, 256, 0, stream>>>(rst, gstats, gamma, beta, out_w, out_b, out);
}

// Round 6
// 156.678 us; speedup vs baseline: 1.9842x; 1.0378x over previous
//
#include <hip/hip_runtime.h>
#include <hip/hip_bf16.h>

#define NN 512
#define DD 64
#define TOPK 20
#define BB 128

// =============== L1: merged kernel =============================================
// blocks 0..127   : k1 topk (4 nodes/block, LDS-staged emb with conflict-free
//                   17-float4 row stride). f64 accumulation order bit-identical
//                   to round-5 (passed) -> identical topk. Block 0 zeroes gstats.
// blocks 128..639 : k2 GEMM, LDS-free hot loop: lane = output column, B-column
//                   in 64 VGPRs, A broadcast via v_readlane (SALU, not LDS pipe).
__global__ __launch_bounds__(256) void L1_fused(const float* __restrict__ data,
                                                const float* __restrict__ emb,
                                                const float* __restrict__ fc_w,
                                                const float* __restrict__ fc_b,
                                                const float* __restrict__ attn_w,
                                                float* __restrict__ z,
                                                float* __restrict__ zsrc,
                                                float* __restrict__ zdst,
                                                int* __restrict__ topk,
                                                float* __restrict__ es_src,
                                                float* __restrict__ es_dst,
                                                double* __restrict__ gstats) {
    __shared__ __align__(16) char smem[34816];
    const int bid = blockIdx.x, t = threadIdx.x;
    const int wid = t >> 6, lane = t & 63;

    if (bid < 128) {
        // ---------------- k1: cos topk ----------------
        float4* lds4 = (float4*)smem;            // [128 rows][17] padded
        const int i = bid * 4 + wid;
        const float4* e4 = (const float4*)emb;

        if (bid == 0 && t < 128) gstats[t] = 0.0;

        float4 wif[16];
        #pragma unroll
        for (int c = 0; c < 16; ++c) wif[c] = e4[i * 16 + c];

        double di = 0.0;
        #pragma unroll
        for (int c = 0; c < 16; ++c) {
            double wx = wif[c].x, wy = wif[c].y, wz = wif[c].z, ww = wif[c].w;
            di += wx * wx; di += wy * wy; di += wz * wz; di += ww * ww;
        }

        double dot[8] = {0,0,0,0,0,0,0,0};
        double dj [8] = {0,0,0,0,0,0,0,0};

        for (int tile = 0; tile < 4; ++tile) {
            __syncthreads();
            for (int m = t; m < 2048; m += 256) {
                const int row = m >> 4, c = m & 15;
                lds4[row * 17 + c] = e4[tile * 2048 + m];   // coalesced global read
            }
            __syncthreads();
            #pragma unroll
            for (int rb = 0; rb < 2; ++rb) {
                const int slot = tile * 2 + rb;
                const int rl = rb * 64 + lane;
                #pragma unroll
                for (int c = 0; c < 16; ++c) {
                    float4 v = lds4[rl * 17 + c];
                    float4 w = wif[c];
                    double vx = v.x, vy = v.y, vz = v.z, vw = v.w;
                    dot[slot] += (double)w.x * vx; dot[slot] += (double)w.y * vy;
                    dot[slot] += (double)w.z * vz; dot[slot] += (double)w.w * vw;
                    dj [slot] += vx * vx; dj[slot] += vy * vy;
                    dj [slot] += vz * vz; dj[slot] += vw * vw;
                }
            }
        }

        const double nrm_i = sqrt(di);
        double v[8];
        #pragma unroll
        for (int s = 0; s < 8; ++s) v[s] = dot[s] / (nrm_i * sqrt(dj[s]));

        for (int k = 0; k < TOPK; ++k) {
            double bv = v[0]; int bs = 0;
            #pragma unroll
            for (int s = 1; s < 8; ++s) if (v[s] > bv) { bv = v[s]; bs = s; }
            int bi = bs * 64 + lane;
            #pragma unroll
            for (int off = 32; off > 0; off >>= 1) {
                double ov = __shfl_xor(bv, off);
                int    oi = __shfl_xor(bi, off);
                if (ov > bv || (ov == bv && oi < bi)) { bv = ov; bi = oi; }
            }
            if (lane == 0) topk[i * TOPK + k] = bi;
            if ((bi & 63) == lane) v[bi >> 6] = -1e300;
        }

        float wf = emb[i * 64 + lane];
        float v1 = wf * attn_w[64 + lane];
        float v2 = wf * attn_w[192 + lane];
        #pragma unroll
        for (int off = 32; off > 0; off >>= 1) {
            v1 += __shfl_xor(v1, off);
            v2 += __shfl_xor(v2, off);
        }
        if (lane == 0) { es_src[i] = v1; es_dst[i] = v2; }
    } else {
        // ---------------- k2: GEMM, 4 waves x 32 rows/block ----------------
        float* WsT = (float*)smem;               // [64 f][65] : WsT[f][d]=fc_w[d][f]
        const float4* fcw4 = (const float4*)fc_w;
        for (int m = t; m < 1024; m += 256) {
            const int d = m >> 4, f4 = m & 15;
            float4 v = fcw4[d * 16 + f4];
            WsT[(f4 * 4 + 0) * 65 + d] = v.x;
            WsT[(f4 * 4 + 1) * 65 + d] = v.y;
            WsT[(f4 * 4 + 2) * 65 + d] = v.z;
            WsT[(f4 * 4 + 3) * 65 + d] = v.w;
        }
        __syncthreads();

        float Breg[64];
        #pragma unroll
        for (int f = 0; f < 64; ++f) Breg[f] = WsT[f * 65 + lane];  // coalesced LDS

        const float bias = fc_b[lane];
        const float aw0  = attn_w[lane];
        const float aw2  = attn_w[128 + lane];
        const long rbase = ((long)(bid - 128) * 4 + wid) * 32;

        #pragma unroll
        for (int g = 0; g < 4; ++g) {
            float a8[8];
            #pragma unroll
            for (int r = 0; r < 8; ++r)
                a8[r] = data[(rbase + g * 8 + r) * 64 + lane];   // coalesced
            #pragma unroll
            for (int r = 0; r < 8; ++r) {
                float acc = 0.f;
                #pragma unroll
                for (int f = 0; f < 64; ++f) {
                    const float af = __int_as_float(
                        __builtin_amdgcn_readlane(__float_as_int(a8[r]), f));
                    acc = fmaf(af, Breg[f], acc);
                }
                const float zb = acc + bias;
                const long row = rbase + g * 8 + r;
                z[row * 64 + lane] = zb;
                float p1 = zb * aw0, p2 = zb * aw2;
                #pragma unroll
                for (int off = 32; off > 0; off >>= 1) {
                    p1 += __shfl_xor(p1, off);
                    p2 += __shfl_xor(p2, off);
                }
                if (lane == 0) { zsrc[row] = p1; zdst[row] = p2; }
            }
        }
    }
}

// =============== K3: LDS-staged gather + one-shot softmax + BN atomics =========
__global__ __launch_bounds__(256) void k3_attn(const float* __restrict__ z,
                                               const float* __restrict__ zsrc,
                                               const float* __restrict__ zdst,
                                               const float* __restrict__ es_src,
                                               const float* __restrict__ es_dst,
                                               const int* __restrict__ topk,
                                               const float* __restrict__ emb,
                                               const float* __restrict__ attn_b_p,
                                               float* __restrict__ rst,
                                               double* __restrict__ gstats) {
    __shared__ float  zs[512 * 16];          // 32 KB
    __shared__ double alf_pool[2560];        // 20 KB: alpha[256][20] / BN-reduce alias
    __shared__ unsigned short sIdx[256 * 20];// 10 KB
    float* alf = (float*)alf_pool;

    const int b    = blockIdx.x >> 2;
    const int dq   = blockIdx.x & 3;
    const int doff = dq * 16;
    const int t    = threadIdx.x;
    const float attn_b = *attn_b_p;
    const long b512 = (long)b * NN;

    float4* zs4 = (float4*)zs;
    for (int m = t; m < 2048; m += 256) {
        const int n = m >> 2, c4i = m & 3;
        zs4[m] = *(const float4*)(z + (b512 + n) * 64 + doff + c4i * 4);
    }
    __syncthreads();

    const int c4 = t & 3;
    const int rq = t >> 2;
    double s1[4] = {0,0,0,0}, s2[4] = {0,0,0,0};

    for (int chunk = 0; chunk < 2; ++chunk) {
        {
            const int n = chunk * 256 + t;
            const float sd = zdst[b512 + n] + es_dst[n] + attn_b;
            float ev[TOPK];
            float m0 = -1e30f;
            #pragma unroll
            for (int tt = 0; tt < TOPK; ++tt) {
                const int s = topk[n + tt * NN];   // scrambled flat edge list
                sIdx[t * TOPK + tt] = (unsigned short)s;
                float e = zsrc[b512 + s] + es_src[s] + sd;
                e = (e >= 0.f) ? e : 0.2f * e;
                ev[tt] = e;
                m0 = fmaxf(m0, e);
            }
            float dsum = 0.f;
            #pragma unroll
            for (int tt = 0; tt < TOPK; ++tt) { ev[tt] = __expf(ev[tt] - m0); dsum += ev[tt]; }
            const float inv = 1.0f / dsum;
            #pragma unroll
            for (int tt = 0; tt < TOPK; ++tt) alf[t * TOPK + tt] = ev[tt] * inv;
        }
        __syncthreads();

        #pragma unroll
        for (int it = 0; it < 4; ++it) {
            const int nl = it * 64 + rq;
            const int n  = chunk * 256 + nl;
            float4 acc = {0.f, 0.f, 0.f, 0.f};
            #pragma unroll
            for (int tt = 0; tt < TOPK; ++tt) {
                const float a = alf[nl * TOPK + tt];
                const float4 zv = zs4[(int)sIdx[nl * TOPK + tt] * 4 + c4];
                acc.x += a * zv.x; acc.y += a * zv.y; acc.z += a * zv.z; acc.w += a * zv.w;
            }
            const float4 ev = *(const float4*)&emb[n * 64 + doff + c4 * 4];
            float4 r;
            r.x = acc.x * ev.x; r.y = acc.y * ev.y; r.z = acc.z * ev.z; r.w = acc.w * ev.w;
            *(float4*)&rst[(b512 + n) * 64 + doff + c4 * 4] = r;
            s1[0] += (double)r.x; s2[0] += (double)r.x * (double)r.x;
            s1[1] += (double)r.y; s2[1] += (double)r.y * (double)r.y;
            s1[2] += (double)r.z; s2[2] += (double)r.z * (double)r.z;
            s1[3] += (double)r.w; s2[3] += (double)r.w * (double)r.w;
        }
        __syncthreads();
    }

    double* r1 = alf_pool;
    double* r2 = alf_pool + 1024;
    #pragma unroll
    for (int j = 0; j < 4; ++j) {
        r1[(c4 * 4 + j) * 64 + rq] = s1[j];
        r2[(c4 * 4 + j) * 64 + rq] = s2[j];
    }
    __syncthreads();
    if (t < 16) {
        double a = 0.0, bb = 0.0;
        for (int q = 0; q < 64; ++q) { a += r1[t * 64 + q]; bb += r2[t * 64 + q]; }
        atomicAdd(&gstats[doff + t], a);
        atomicAdd(&gstats[64 + doff + t], bb);
    }
}

// =============== K5: BN finalize (per-block) + apply + ReLU + out_w dot ========
__global__ __launch_bounds__(256) void k5_out(const float* __restrict__ rst,
                                              const double* __restrict__ gstats,
                                              const float* __restrict__ gamma,
                                              const float* __restrict__ beta,
                                              const float* __restrict__ out_w,
                                              const float* __restrict__ out_b_p,
                                              float* __restrict__ out) {
    __shared__ float scv[64], biv[64];
    const int t = threadIdx.x;
    if (t < 64) {
        const double M = (double)BB * (double)NN;
        const double s  = gstats[t];
        const double s2 = gstats[64 + t];
        const double mu  = s / M;
        const double var = s2 / M - mu * mu;
        const float scale = (float)((double)gamma[t] / sqrt(var + 1e-5));
        scv[t] = scale;
        biv[t] = beta[t] - (float)mu * scale;
    }
    __syncthreads();

    const int wid = t >> 6, lane = t & 63;
    const float sc = scv[lane], bi = biv[lane], ow = out_w[lane];
    const float ob = *out_b_p;
    const long rowbase = (long)blockIdx.x * 16 + wid * 4;
    float v[4];
    #pragma unroll
    for (int rr = 0; rr < 4; ++rr)
        v[rr] = fmaxf(rst[(rowbase + rr) * 64 + lane] * sc + bi, 0.f) * ow;
    #pragma unroll
    for (int off = 32; off > 0; off >>= 1)
        #pragma unroll
        for (int rr = 0; rr < 4; ++rr) v[rr] += __shfl_down(v[rr], off);
    if (lane == 0)
        #pragma unroll
        for (int rr = 0; rr < 4; ++rr) out[rowbase + rr] = v[rr] + ob;
}

extern "C" void kernel_launch(void* const* d_in, const int* in_sizes, int n_in,
                              void* d_out, int out_size, void* d_ws, size_t ws_size,
                              hipStream_t stream) {
    const float* data   = (const float*)d_in[0];
    const float* emb    = (const float*)d_in[1];
    const float* fc_w   = (const float*)d_in[2];
    const float* fc_b   = (const float*)d_in[3];
    const float* attn_w = (const float*)d_in[4];
    const float* attn_b = (const float*)d_in[5];
    const float* gamma  = (const float*)d_in[6];
    const float* beta   = (const float*)d_in[7];
    const float* out_w  = (const float*)d_in[8];
    const float* out_b  = (const float*)d_in[9];
    float* out = (float*)d_out;

    char* ws = (char*)d_ws;
    float*  z      = (float*) (ws + 0);            // 16 MB
    float*  rst    = (float*) (ws + 16777216);     // 16 MB
    float*  zsrc   = (float*) (ws + 33554432);     // 256 KB
    float*  zdst   = (float*) (ws + 33816576);     // 256 KB
    int*    topk   = (int*)   (ws + 34078720);     // 40 KB
    float*  es_src = (float*) (ws + 34119680);     // 2 KB
    float*  es_dst = (float*) (ws + 34121728);     // 2 KB
    double* gstats = (double*)(ws + 34123776);     // 1 KB

    L1_fused<<<640, 256, 0, stream>>>(data, emb, fc_w, fc_b, attn_w,
                                      z, zsrc, zdst, topk, es_src, es_dst, gstats);
    k3_attn<<<BB * 4, 256, 0, stream>>>(z, zsrc, zdst, es_src, es_dst, topk, emb,
                                        attn_b, rst, gstats);
    k5_out<<<4096, 256, 0, stream>>>(rst, gstats, gamma, beta, out_w, out_b, out);
}

// Round 7
// 155.830 us; speedup vs baseline: 1.9950x; 1.0054x over previous
//
#include <hip/hip_runtime.h>
#include <hip/hip_bf16.h>

#define NN 512
#define DD 64
#define TOPK 20
#define BB 128

// =============== L1: merged kernel =============================================
// blocks 0..127   : k1 topk. Register-lean: query rows staged in LDS (broadcast
//                   reads), candidate slots processed sequentially with scalar
//                   f64 accumulators -> no spills. Accumulation order bit-
//                   identical to round-6 (passed) -> identical topk.
// blocks 128..639 : k2 GEMM (unchanged from round 6): lane = output column,
//                   B-column in 64 VGPRs, A broadcast via v_readlane.
__global__ __launch_bounds__(256) void L1_fused(const float* __restrict__ data,
                                                const float* __restrict__ emb,
                                                const float* __restrict__ fc_w,
                                                const float* __restrict__ fc_b,
                                                const float* __restrict__ attn_w,
                                                float* __restrict__ z,
                                                float* __restrict__ zsrc,
                                                float* __restrict__ zdst,
                                                int* __restrict__ topk,
                                                float* __restrict__ es_src,
                                                float* __restrict__ es_dst,
                                                double* __restrict__ gstats) {
    __shared__ __align__(16) char smem[36864];
    const int bid = blockIdx.x, t = threadIdx.x;
    const int wid = t >> 6, lane = t & 63;

    if (bid < 128) {
        // ---------------- k1: cos topk ----------------
        float4* lds4 = (float4*)smem;              // [128 rows][17] padded tile
        float4* wis4 = (float4*)(smem + 34816);    // [4 nodes][16] query rows
        const int i = bid * 4 + wid;
        const float4* e4 = (const float4*)emb;

        if (bid == 0 && t < 128) gstats[t] = 0.0;

        if (t < 64) wis4[t] = e4[(bid * 4 + (t >> 4)) * 16 + (t & 15)];
        __syncthreads();

        // di: f64, c ascending, x,y,z,w (bit-identical to R6)
        double di = 0.0;
        #pragma unroll
        for (int c = 0; c < 16; ++c) {
            const float4 w = wis4[wid * 16 + c];
            const double wx = w.x, wy = w.y, wz = w.z, ww = w.w;
            di += wx * wx; di += wy * wy; di += wz * wz; di += ww * ww;
        }
        const double nrm_i = sqrt(di);

        double v[8];
        for (int tile = 0; tile < 4; ++tile) {
            __syncthreads();
            for (int m = t; m < 2048; m += 256) {
                const int row = m >> 4, c = m & 15;
                lds4[row * 17 + c] = e4[tile * 2048 + m];   // coalesced global read
            }
            __syncthreads();
            #pragma unroll
            for (int rb = 0; rb < 2; ++rb) {
                const int slot = tile * 2 + rb;
                const int rl = rb * 64 + lane;
                double dot = 0.0, dj = 0.0;
                #pragma unroll
                for (int c = 0; c < 16; ++c) {
                    const float4 vv = lds4[rl * 17 + c];
                    const float4 w  = wis4[wid * 16 + c];   // same-addr broadcast
                    const double vx = vv.x, vy = vv.y, vz = vv.z, vw = vv.w;
                    dot += (double)w.x * vx; dot += (double)w.y * vy;
                    dot += (double)w.z * vz; dot += (double)w.w * vw;
                    dj  += vx * vx; dj += vy * vy; dj += vz * vz; dj += vw * vw;
                }
                v[slot] = dot / (nrm_i * sqrt(dj));
            }
        }

        for (int k = 0; k < TOPK; ++k) {
            double bv = v[0]; int bs = 0;
            #pragma unroll
            for (int s = 1; s < 8; ++s) if (v[s] > bv) { bv = v[s]; bs = s; }
            int bi = bs * 64 + lane;
            #pragma unroll
            for (int off = 32; off > 0; off >>= 1) {
                double ov = __shfl_xor(bv, off);
                int    oi = __shfl_xor(bi, off);
                if (ov > bv || (ov == bv && oi < bi)) { bv = ov; bi = oi; }
            }
            if (lane == 0) topk[i * TOPK + k] = bi;
            if ((bi & 63) == lane) v[bi >> 6] = -1e300;
        }

        float wf = emb[i * 64 + lane];
        float v1 = wf * attn_w[64 + lane];
        float v2 = wf * attn_w[192 + lane];
        #pragma unroll
        for (int off = 32; off > 0; off >>= 1) {
            v1 += __shfl_xor(v1, off);
            v2 += __shfl_xor(v2, off);
        }
        if (lane == 0) { es_src[i] = v1; es_dst[i] = v2; }
    } else {
        // ---------------- k2: GEMM, 4 waves x 32 rows/block (unchanged) --------
        float* WsT = (float*)smem;               // [64 f][65] : WsT[f][d]=fc_w[d][f]
        const float4* fcw4 = (const float4*)fc_w;
        for (int m = t; m < 1024; m += 256) {
            const int d = m >> 4, f4 = m & 15;
            float4 v = fcw4[d * 16 + f4];
            WsT[(f4 * 4 + 0) * 65 + d] = v.x;
            WsT[(f4 * 4 + 1) * 65 + d] = v.y;
            WsT[(f4 * 4 + 2) * 65 + d] = v.z;
            WsT[(f4 * 4 + 3) * 65 + d] = v.w;
        }
        __syncthreads();

        float Breg[64];
        #pragma unroll
        for (int f = 0; f < 64; ++f) Breg[f] = WsT[f * 65 + lane];  // coalesced LDS

        const float bias = fc_b[lane];
        const float aw0  = attn_w[lane];
        const float aw2  = attn_w[128 + lane];
        const long rbase = ((long)(bid - 128) * 4 + wid) * 32;

        #pragma unroll
        for (int g = 0; g < 4; ++g) {
            float a8[8];
            #pragma unroll
            for (int r = 0; r < 8; ++r)
                a8[r] = data[(rbase + g * 8 + r) * 64 + lane];   // coalesced
            #pragma unroll
            for (int r = 0; r < 8; ++r) {
                float acc = 0.f;
                #pragma unroll
                for (int f = 0; f < 64; ++f) {
                    const float af = __int_as_float(
                        __builtin_amdgcn_readlane(__float_as_int(a8[r]), f));
                    acc = fmaf(af, Breg[f], acc);
                }
                const float zb = acc + bias;
                const long row = rbase + g * 8 + r;
                z[row * 64 + lane] = zb;
                float p1 = zb * aw0, p2 = zb * aw2;
                #pragma unroll
                for (int off = 32; off > 0; off >>= 1) {
                    p1 += __shfl_xor(p1, off);
                    p2 += __shfl_xor(p2, off);
                }
                if (lane == 0) { zsrc[row] = p1; zdst[row] = p2; }
            }
        }
    }
}

// =============== K3: LDS-staged gather + one-shot softmax + BN atomics =========
__global__ __launch_bounds__(256) void k3_attn(const float* __restrict__ z,
                                               const float* __restrict__ zsrc,
                                               const float* __restrict__ zdst,
                                               const float* __restrict__ es_src,
                                               const float* __restrict__ es_dst,
                                               const int* __restrict__ topk,
                                               const float* __restrict__ emb,
                                               const float* __restrict__ attn_b_p,
                                               float* __restrict__ rst,
                                               double* __restrict__ gstats) {
    __shared__ float  zs[512 * 16];          // 32 KB
    __shared__ double alf_pool[2560];        // 20 KB: alpha[256][20] / BN-reduce alias
    __shared__ unsigned short sIdx[256 * 20];// 10 KB
    float* alf = (float*)alf_pool;

    const int b    = blockIdx.x >> 2;
    const int dq   = blockIdx.x & 3;
    const int doff = dq * 16;
    const int t    = threadIdx.x;
    const float attn_b = *attn_b_p;
    const long b512 = (long)b * NN;

    float4* zs4 = (float4*)zs;
    for (int m = t; m < 2048; m += 256) {
        const int n = m >> 2, c4i = m & 3;
        zs4[m] = *(const float4*)(z + (b512 + n) * 64 + doff + c4i * 4);
    }
    __syncthreads();

    const int c4 = t & 3;
    const int rq = t >> 2;
    double s1[4] = {0,0,0,0}, s2[4] = {0,0,0,0};

    for (int chunk = 0; chunk < 2; ++chunk) {
        {
            const int n = chunk * 256 + t;
            const float sd = zdst[b512 + n] + es_dst[n] + attn_b;
            float ev[TOPK];
            float m0 = -1e30f;
            #pragma unroll
            for (int tt = 0; tt < TOPK; ++tt) {
                const int s = topk[n + tt * NN];   // scrambled flat edge list
                sIdx[t * TOPK + tt] = (unsigned short)s;
                float e = zsrc[b512 + s] + es_src[s] + sd;
                e = (e >= 0.f) ? e : 0.2f * e;
                ev[tt] = e;
                m0 = fmaxf(m0, e);
            }
            float dsum = 0.f;
            #pragma unroll
            for (int tt = 0; tt < TOPK; ++tt) { ev[tt] = __expf(ev[tt] - m0); dsum += ev[tt]; }
            const float inv = 1.0f / dsum;
            #pragma unroll
            for (int tt = 0; tt < TOPK; ++tt) alf[t * TOPK + tt] = ev[tt] * inv;
        }
        __syncthreads();

        #pragma unroll
        for (int it = 0; it < 4; ++it) {
            const int nl = it * 64 + rq;
            const int n  = chunk * 256 + nl;
            float4 acc = {0.f, 0.f, 0.f, 0.f};
            #pragma unroll
            for (int tt = 0; tt < TOPK; ++tt) {
                const float a = alf[nl * TOPK + tt];
                const float4 zv = zs4[(int)sIdx[nl * TOPK + tt] * 4 + c4];
                acc.x += a * zv.x; acc.y += a * zv.y; acc.z += a * zv.z; acc.w += a * zv.w;
            }
            const float4 ev = *(const float4*)&emb[n * 64 + doff + c4 * 4];
            float4 r;
            r.x = acc.x * ev.x; r.y = acc.y * ev.y; r.z = acc.z * ev.z; r.w = acc.w * ev.w;
            *(float4*)&rst[(b512 + n) * 64 + doff + c4 * 4] = r;
            s1[0] += (double)r.x; s2[0] += (double)r.x * (double)r.x;
            s1[1] += (double)r.y; s2[1] += (double)r.y * (double)r.y;
            s1[2] += (double)r.z; s2[2] += (double)r.z * (double)r.z;
            s1[3] += (double)r.w; s2[3] += (double)r.w * (double)r.w;
        }
        __syncthreads();
    }

    double* r1 = alf_pool;
    double* r2 = alf_pool + 1024;
    #pragma unroll
    for (int j = 0; j < 4; ++j) {
        r1[(c4 * 4 + j) * 64 + rq] = s1[j];
        r2[(c4 * 4 + j) * 64 + rq] = s2[j];
    }
    __syncthreads();
    if (t < 16) {
        double a = 0.0, bb = 0.0;
        for (int q = 0; q < 64; ++q) { a += r1[t * 64 + q]; bb += r2[t * 64 + q]; }
        atomicAdd(&gstats[doff + t], a);
        atomicAdd(&gstats[64 + doff + t], bb);
    }
}

// =============== K5: BN finalize (per-block) + apply + ReLU + out_w dot ========
__global__ __launch_bounds__(256) void k5_out(const float* __restrict__ rst,
                                              const double* __restrict__ gstats,
                                              const float* __restrict__ gamma,
                                              const float* __restrict__ beta,
                                              const float* __restrict__ out_w,
                                              const float* __restrict__ out_b_p,
                                              float* __restrict__ out) {
    __shared__ float scv[64], biv[64];
    const int t = threadIdx.x;
    if (t < 64) {
        const double M = (double)BB * (double)NN;
        const double s  = gstats[t];
        const double s2 = gstats[64 + t];
        const double mu  = s / M;
        const double var = s2 / M - mu * mu;
        const float scale = (float)((double)gamma[t] / sqrt(var + 1e-5));
        scv[t] = scale;
        biv[t] = beta[t] - (float)mu * scale;
    }
    __syncthreads();

    const int wid = t >> 6, lane = t & 63;
    const float sc = scv[lane], bi = biv[lane], ow = out_w[lane];
    const float ob = *out_b_p;
    const long rowbase = (long)blockIdx.x * 16 + wid * 4;
    float v[4];
    #pragma unroll
    for (int rr = 0; rr < 4; ++rr)
        v[rr] = fmaxf(rst[(rowbase + rr) * 64 + lane] * sc + bi, 0.f) * ow;
    #pragma unroll
    for (int off = 32; off > 0; off >>= 1)
        #pragma unroll
        for (int rr = 0; rr < 4; ++rr) v[rr] += __shfl_down(v[rr], off);
    if (lane == 0)
        #pragma unroll
        for (int rr = 0; rr < 4; ++rr) out[rowbase + rr] = v[rr] + ob;
}

extern "C" void kernel_launch(void* const* d_in, const int* in_sizes, int n_in,
                              void* d_out, int out_size, void* d_ws, size_t ws_size,
                              hipStream_t stream) {
    const float* data   = (const float*)d_in[0];
    const float* emb    = (const float*)d_in[1];
    const float* fc_w   = (const float*)d_in[2];
    const float* fc_b   = (const float*)d_in[3];
    const float* attn_w = (const float*)d_in[4];
    const float* attn_b = (const float*)d_in[5];
    const float* gamma  = (const float*)d_in[6];
    const float* beta   = (const float*)d_in[7];
    const float* out_w  = (const float*)d_in[8];
    const float* out_b  = (const float*)d_in[9];
    float* out = (float*)d_out;

    char* ws = (char*)d_ws;
    float*  z      = (float*) (ws + 0);            // 16 MB
    float*  rst    = (float*) (ws + 16777216);     // 16 MB
    float*  zsrc   = (float*) (ws + 33554432);     // 256 KB
    float*  zdst   = (float*) (ws + 33816576);     // 256 KB
    int*    topk   = (int*)   (ws + 34078720);     // 40 KB
    float*  es_src = (float*) (ws + 34119680);     // 2 KB
    float*  es_dst = (float*) (ws + 34121728);     // 2 KB
    double* gstats = (double*)(ws + 34123776);     // 1 KB

    L1_fused<<<640, 256, 0, stream>>>(data, emb, fc_w, fc_b, attn_w,
                                      z, zsrc, zdst, topk, es_src, es_dst, gstats);
    k3_attn<<<BB * 4, 256, 0, stream>>>(z, zsrc, zdst, es_src, es_dst, topk, emb,
                                        attn_b, rst, gstats);
    k5_out<<<4096, 256, 0, stream>>>(rst, gstats, gamma, beta, out_w, out_b, out);
}